// Round 6
// baseline (146.807 us; speedup 1.0000x reference)
//
#include <hip/hip_runtime.h>
#include <hip/hip_fp16.h>
#include <hip/hip_cooperative_groups.h>

#define D_DIM 4096
#define H_DIM 4096
#define HS 128              // h-rows per block
#define IS 512              // i-cols per block
#define NE (D_DIM / IS)     // 8 i-chunks
#define NS (H_DIM / HS)     // 32 h-slabs
#define SPAD 520            // padded fp16 row stride (1040 B -> +4 banks/row)

namespace cg = cooperative_groups;

__device__ __forceinline__ float fast_sigmoid(float a) {
    return __builtin_amdgcn_rcpf(1.0f + __expf(-a));
}

// Cooperative kernel, grid = NS*NE = 256 blocks x 1024 threads, 1 block/CU.
// Block (s,e): h-slab s (128 rows), i-chunk e (512 cols).
// P1: per-row local exclusive scans -> LDS (raw fp16), chunk totals -> Tws.
// grid.sync()
// P2: base = c[h] + sum of predecessor-chunk totals; sigmoid in-LDS.
// P3: partial[i] = sum_{h in slab} v[i,h] * S[h,i]; v read 2x256B adjacent.
__global__ __launch_bounds__(1024, 1) void nade_coop_kernel(
    const float* __restrict__ x,
    const float* __restrict__ w,
    const float* __restrict__ v,
    const float* __restrict__ c,
    float* __restrict__ Tws,     // [NE][H_DIM] chunk totals
    float* __restrict__ part)    // [NS][D_DIM] partial logits
{
    __shared__ __half S[HS][SPAD];   // 130 KB

    const int tid  = threadIdx.x;
    const int wv   = tid >> 6;
    const int lane = tid & 63;
    const int s    = blockIdx.x >> 3;
    const int e    = blockIdx.x & 7;
    const int h0   = s * HS;
    const int i0   = e * IS;

    // ---------------- P1: local scans (wave wv owns rows wv*8 .. wv*8+7) ----
    const float* xp = x + i0 + 8 * lane;
    float4 x0 = *reinterpret_cast<const float4*>(xp);
    float4 x1 = *reinterpret_cast<const float4*>(xp + 4);

    const float* wbase = w + ((size_t)(h0 + wv * 8)) * D_DIM + i0 + 8 * lane;

    float4 wc0 = *reinterpret_cast<const float4*>(wbase);
    float4 wc1 = *reinterpret_cast<const float4*>(wbase + 4);

    #pragma unroll
    for (int k = 0; k < 8; ++k) {
        float4 wn0, wn1;
        if (k < 7) {
            const float* p = wbase + (size_t)(k + 1) * D_DIM;
            wn0 = *reinterpret_cast<const float4*>(p);
            wn1 = *reinterpret_cast<const float4*>(p + 4);
        }
        // products
        float p0 = wc0.x * x0.x, p1 = wc0.y * x0.y, p2 = wc0.z * x0.z, p3 = wc0.w * x0.w;
        float p4 = wc1.x * x1.x, p5 = wc1.y * x1.y, p6 = wc1.z * x1.z, p7 = wc1.w * x1.w;
        float s8 = ((p0 + p1) + (p2 + p3)) + ((p4 + p5) + (p6 + p7));
        float incl = s8;
        #pragma unroll
        for (int off = 1; off < 64; off <<= 1) {
            float tv = __shfl_up(incl, off, 64);
            incl += (lane >= off) ? tv : 0.0f;
        }
        // local exclusive per-position values (no base, no sigmoid yet)
        float a = incl - s8;
        float l0 = a;       a += p0;
        float l1 = a;       a += p1;
        float l2 = a;       a += p2;
        float l3 = a;       a += p3;
        float l4 = a;       a += p4;
        float l5 = a;       a += p5;
        float l6 = a;       a += p6;
        float l7 = a;
        union { __half2 h2[4]; uint4 u; } P;
        P.h2[0] = __floats2half2_rn(l0, l1);
        P.h2[1] = __floats2half2_rn(l2, l3);
        P.h2[2] = __floats2half2_rn(l4, l5);
        P.h2[3] = __floats2half2_rn(l6, l7);
        const int row = wv * 8 + k;
        *reinterpret_cast<uint4*>(&S[row][8 * lane]) = P.u;
        if (lane == 63) Tws[e * H_DIM + h0 + row] = incl;   // chunk total
        wc0 = wn0; wc1 = wn1;
    }

    __threadfence();
    cg::this_grid().sync();

    // ---------------- P2: add base, sigmoid in-LDS ----------------
    {
        const int row = tid >> 3;        // 128 rows x 8 threads
        const int sub = tid & 7;
        float base = c[h0 + row];
        for (int ee = 0; ee < e; ++ee)
            base += Tws[ee * H_DIM + h0 + row];
        #pragma unroll
        for (int k = 0; k < 8; ++k) {
            const int m = sub + 8 * k;   // interleaved 16B chunks (bank-friendly)
            uint4* p = reinterpret_cast<uint4*>(&S[row][m * 8]);
            union { __half2 h2[4]; uint4 u; } P;
            P.u = *p;
            #pragma unroll
            for (int j = 0; j < 4; ++j) {
                float2 f = __half22float2(P.h2[j]);
                f.x = fast_sigmoid(f.x + base);
                f.y = fast_sigmoid(f.y + base);
                P.h2[j] = __floats2half2_rn(f.x, f.y);
            }
            *p = P.u;
        }
    }
    __syncthreads();

    // ---------------- P3: v-dot (thread pair per i, 2x256B adjacent) -------
    {
        const int il   = tid >> 1;      // 512 i's
        const int half = tid & 1;
        const int i    = i0 + il;
        const float* vp = v + (size_t)i * H_DIM + h0 + half * 64;
        float acc0 = 0.0f, acc1 = 0.0f;
        #pragma unroll
        for (int k = 0; k < 8; ++k) {
            float4 va = *reinterpret_cast<const float4*>(vp + 8 * k);
            float4 vb = *reinterpret_cast<const float4*>(vp + 8 * k + 4);
            const int hh = half * 64 + 8 * k;
            acc0 += va.x * __half2float(S[hh + 0][il])
                  + va.y * __half2float(S[hh + 1][il])
                  + va.z * __half2float(S[hh + 2][il])
                  + va.w * __half2float(S[hh + 3][il]);
            acc1 += vb.x * __half2float(S[hh + 4][il])
                  + vb.y * __half2float(S[hh + 5][il])
                  + vb.z * __half2float(S[hh + 6][il])
                  + vb.w * __half2float(S[hh + 7][il]);
        }
        float acc = acc0 + acc1;
        acc += __shfl_xor(acc, 1, 64);
        if (half == 0) part[(size_t)s * D_DIM + i] = acc;
    }
}

// out[i] = sigmoid(b[i] + sum_{s<32} part[s][i]). Grid 16 x 1024.
__global__ __launch_bounds__(1024, 1) void nade_out_kernel(
    const float* __restrict__ part,
    const float* __restrict__ b,
    float* __restrict__ out)
{
    __shared__ float red[4][260];
    const int tid = threadIdx.x;
    const int il  = tid & 255;
    const int g   = tid >> 8;           // 4 groups of 8 slabs
    const int i   = blockIdx.x * 256 + il;
    float sacc = 0.0f;
    #pragma unroll
    for (int j = 0; j < 8; ++j)
        sacc += part[(size_t)(g * 8 + j) * D_DIM + i];
    red[g][il] = sacc;
    __syncthreads();
    if (g == 0) {
        float t = b[i] + red[0][il] + red[1][il] + red[2][il] + red[3][il];
        out[i] = fast_sigmoid(t);
    }
}

extern "C" void kernel_launch(void* const* d_in, const int* in_sizes, int n_in,
                              void* d_out, int out_size, void* d_ws, size_t ws_size,
                              hipStream_t stream)
{
    const float* x = (const float*)d_in[0];
    const float* w = (const float*)d_in[1];
    const float* b = (const float*)d_in[2];
    const float* v = (const float*)d_in[3];
    const float* c = (const float*)d_in[4];
    float* out = (float*)d_out;

    float* Tws  = (float*)d_ws;                    // [NE][H_DIM]  = 128 KB
    float* part = Tws + (size_t)NE * H_DIM;        // [NS][D_DIM]  = 512 KB

    void* args[] = { (void*)&x, (void*)&w, (void*)&v, (void*)&c,
                     (void*)&Tws, (void*)&part };
    hipLaunchCooperativeKernel((const void*)nade_coop_kernel,
                               dim3(NS * NE), dim3(1024), args, 0, stream);
    nade_out_kernel<<<16, 1024, 0, stream>>>(part, b, out);
}

// Round 7
// 42.499 us; speedup vs baseline: 3.4544x; 3.4544x over previous
//
#include <hip/hip_runtime.h>
#include <hip/hip_fp16.h>

#define D_DIM 4096
#define H_DIM 4096
#define HB 16                 // rows (h) per block; 64B v-line granularity per block
#define BLK 1024              // 16 waves; wave wv owns row h0+wv
#define NBLK (H_DIM / HB)     // 256 blocks = 1 per CU
#define TILE 512              // scan tile: 8 floats per lane

__device__ __forceinline__ float fast_sigmoid(float a) {
    return __builtin_amdgcn_rcpf(1.0f + __expf(-a));
}

__device__ __forceinline__ float2 h2_to_f2(unsigned u) {
    union { unsigned u; __half2 h; } cvt;
    cvt.u = u;
    return __half22float2(cvt.h);
}

// Phase 1: each wave scans its full row into a 128 KB fp16 LDS tile (no sync).
// Phase 2: each thread dots 4 columns against 4 v rows; ALL 16 v float4 loads
// and ALL 16 S uint2 reads are issued as named registers BEFORE consumption,
// pinned by sched_barrier(0) -> ~64 KB/CU of global reads in flight.
template <bool ATOMIC>
__global__ __launch_bounds__(BLK, 4) void nade_main_kernel(
    const float* __restrict__ x,
    const float* __restrict__ w,
    const float* __restrict__ v,
    const float* __restrict__ c,
    float* __restrict__ part)
{
    __shared__ __half S[HB][D_DIM];   // 16 x 4096 fp16 = 128 KB

    const int tid  = threadIdx.x;
    const int wv   = tid >> 6;
    const int lane = tid & 63;
    const int h0   = blockIdx.x * HB;

    // ---------------- Phase 1: scan (no barriers) ----------------
    const float* wrow = w + (size_t)(h0 + wv) * D_DIM + 8 * lane;
    float carry = c[h0 + wv];

    float4 wA0 = *reinterpret_cast<const float4*>(wrow + 0 * TILE);
    float4 wA1 = *reinterpret_cast<const float4*>(wrow + 0 * TILE + 4);
    float4 wB0 = *reinterpret_cast<const float4*>(wrow + 1 * TILE);
    float4 wB1 = *reinterpret_cast<const float4*>(wrow + 1 * TILE + 4);

    auto scan_tile = [&](int t, float4 w0, float4 w1) {
        const float* xp = x + t * TILE + 8 * lane;
        float4 x0 = *reinterpret_cast<const float4*>(xp);
        float4 x1 = *reinterpret_cast<const float4*>(xp + 4);
        float p0 = w0.x * x0.x, p1 = w0.y * x0.y, p2 = w0.z * x0.z, p3 = w0.w * x0.w;
        float p4 = w1.x * x1.x, p5 = w1.y * x1.y, p6 = w1.z * x1.z, p7 = w1.w * x1.w;
        float s8 = ((p0 + p1) + (p2 + p3)) + ((p4 + p5) + (p6 + p7));
        float incl = s8;
        #pragma unroll
        for (int off = 1; off < 64; off <<= 1) {
            float tv = __shfl_up(incl, off, 64);
            incl += (lane >= off) ? tv : 0.0f;
        }
        float tot = __shfl(incl, 63, 64);
        float a = carry + incl - s8;          // pre-activation of lane's col 0
        float sg0 = fast_sigmoid(a); a += p0;
        float sg1 = fast_sigmoid(a); a += p1;
        float sg2 = fast_sigmoid(a); a += p2;
        float sg3 = fast_sigmoid(a); a += p3;
        float sg4 = fast_sigmoid(a); a += p4;
        float sg5 = fast_sigmoid(a); a += p5;
        float sg6 = fast_sigmoid(a); a += p6;
        float sg7 = fast_sigmoid(a);
        carry += tot;
        union { __half2 h2[4]; uint4 u; } P;
        P.h2[0] = __floats2half2_rn(sg0, sg1);
        P.h2[1] = __floats2half2_rn(sg2, sg3);
        P.h2[2] = __floats2half2_rn(sg4, sg5);
        P.h2[3] = __floats2half2_rn(sg6, sg7);
        *reinterpret_cast<uint4*>(&S[wv][t * TILE + 8 * lane]) = P.u;  // b128
    };

    scan_tile(0, wA0, wA1);
    wA0 = *reinterpret_cast<const float4*>(wrow + 2 * TILE);
    wA1 = *reinterpret_cast<const float4*>(wrow + 2 * TILE + 4);
    scan_tile(1, wB0, wB1);
    wB0 = *reinterpret_cast<const float4*>(wrow + 3 * TILE);
    wB1 = *reinterpret_cast<const float4*>(wrow + 3 * TILE + 4);
    scan_tile(2, wA0, wA1);
    wA0 = *reinterpret_cast<const float4*>(wrow + 4 * TILE);
    wA1 = *reinterpret_cast<const float4*>(wrow + 4 * TILE + 4);
    scan_tile(3, wB0, wB1);
    wB0 = *reinterpret_cast<const float4*>(wrow + 5 * TILE);
    wB1 = *reinterpret_cast<const float4*>(wrow + 5 * TILE + 4);
    scan_tile(4, wA0, wA1);
    wA0 = *reinterpret_cast<const float4*>(wrow + 6 * TILE);
    wA1 = *reinterpret_cast<const float4*>(wrow + 6 * TILE + 4);
    scan_tile(5, wB0, wB1);
    wB0 = *reinterpret_cast<const float4*>(wrow + 7 * TILE);
    wB1 = *reinterpret_cast<const float4*>(wrow + 7 * TILE + 4);
    scan_tile(6, wA0, wA1);
    scan_tile(7, wB0, wB1);

    __syncthreads();   // the ONLY barrier

    // ---------------- Phase 2: reduce, MLP-forced ----------------
    const int i0 = 4 * tid;
    const float* vp0 = v + (size_t)i0 * H_DIM + h0;
    const float* vp1 = vp0 + H_DIM;
    const float* vp2 = vp0 + 2 * (size_t)H_DIM;
    const float* vp3 = vp0 + 3 * (size_t)H_DIM;

#define LD4(p, o) (*reinterpret_cast<const float4*>((p) + (o)))
    // --- issue ALL 16 v lines (4 rows x 64 B), named regs ---
    float4 va0 = LD4(vp0, 0), va1 = LD4(vp0, 4), va2 = LD4(vp0, 8),  va3 = LD4(vp0, 12);
    float4 vb0 = LD4(vp1, 0), vb1 = LD4(vp1, 4), vb2 = LD4(vp1, 8),  vb3 = LD4(vp1, 12);
    float4 vc0 = LD4(vp2, 0), vc1 = LD4(vp2, 4), vc2 = LD4(vp2, 8),  vc3 = LD4(vp2, 12);
    float4 vd0 = LD4(vp3, 0), vd1 = LD4(vp3, 4), vd2 = LD4(vp3, 8),  vd3 = LD4(vp3, 12);
#undef LD4
    // --- issue ALL 16 S column reads (LDS, returns under v latency) ---
#define LDS2(h) (*reinterpret_cast<const uint2*>(&S[h][i0]))
    uint2 s0 = LDS2(0),  s1 = LDS2(1),  s2 = LDS2(2),  s3 = LDS2(3);
    uint2 s4 = LDS2(4),  s5 = LDS2(5),  s6 = LDS2(6),  s7 = LDS2(7);
    uint2 s8 = LDS2(8),  s9 = LDS2(9),  s10 = LDS2(10), s11 = LDS2(11);
    uint2 s12 = LDS2(12), s13 = LDS2(13), s14 = LDS2(14), s15 = LDS2(15);
#undef LDS2
    __builtin_amdgcn_sched_barrier(0);   // nothing above sinks below

    float acc0 = 0.0f, acc1 = 0.0f, acc2 = 0.0f, acc3 = 0.0f;
#define ACC4(vq, h2a, h2b, h2c, h2d)                                   \
    {                                                                   \
        float2 f0 = h2_to_f2(h2a), f1 = h2_to_f2(h2b);                 \
        float2 f2 = h2_to_f2(h2c), f3 = h2_to_f2(h2d);                 \
        (void)0;                                                        \
        accX += vq.x * f0.FLD + vq.y * f1.FLD + vq.z * f2.FLD + vq.w * f3.FLD; \
    }
    // row i0   : .x words, low halves
#define accX acc0
#define FLD x
    ACC4(va0, s0.x,  s1.x,  s2.x,  s3.x)
    ACC4(va1, s4.x,  s5.x,  s6.x,  s7.x)
    ACC4(va2, s8.x,  s9.x,  s10.x, s11.x)
    ACC4(va3, s12.x, s13.x, s14.x, s15.x)
#undef FLD
#undef accX
    // row i0+1 : .x words, high halves
#define accX acc1
#define FLD y
    ACC4(vb0, s0.x,  s1.x,  s2.x,  s3.x)
    ACC4(vb1, s4.x,  s5.x,  s6.x,  s7.x)
    ACC4(vb2, s8.x,  s9.x,  s10.x, s11.x)
    ACC4(vb3, s12.x, s13.x, s14.x, s15.x)
#undef FLD
#undef accX
    // row i0+2 : .y words, low halves
#define accX acc2
#define FLD x
    ACC4(vc0, s0.y,  s1.y,  s2.y,  s3.y)
    ACC4(vc1, s4.y,  s5.y,  s6.y,  s7.y)
    ACC4(vc2, s8.y,  s9.y,  s10.y, s11.y)
    ACC4(vc3, s12.y, s13.y, s14.y, s15.y)
#undef FLD
#undef accX
    // row i0+3 : .y words, high halves
#define accX acc3
#define FLD y
    ACC4(vd0, s0.y,  s1.y,  s2.y,  s3.y)
    ACC4(vd1, s4.y,  s5.y,  s6.y,  s7.y)
    ACC4(vd2, s8.y,  s9.y,  s10.y, s11.y)
    ACC4(vd3, s12.y, s13.y, s14.y, s15.y)
#undef FLD
#undef accX
#undef ACC4

    if (ATOMIC) {
        atomicAdd(&part[i0 + 0], acc0);
        atomicAdd(&part[i0 + 1], acc1);
        atomicAdd(&part[i0 + 2], acc2);
        atomicAdd(&part[i0 + 3], acc3);
    } else {
        float4 o; o.x = acc0; o.y = acc1; o.z = acc2; o.w = acc3;
        *reinterpret_cast<float4*>(part + (size_t)blockIdx.x * D_DIM + i0) = o;
    }
}

// Grid: D/64 blocks x 1024 threads. Sums the [NBLK][D] partial matrix (coalesced).
__global__ __launch_bounds__(1024, 1) void nade_reduce_kernel(
    const float* __restrict__ part,
    const float* __restrict__ b,
    float* __restrict__ out)
{
    __shared__ float red[16][64];
    const int tid = threadIdx.x;
    const int bg  = tid >> 6;      // wave id 0..15
    const int il  = tid & 63;
    const int i   = blockIdx.x * 64 + il;
    float s = 0.0f;
    #pragma unroll
    for (int j = 0; j < NBLK / 16; ++j)
        s += part[(size_t)(bg * (NBLK / 16) + j) * D_DIM + i];
    red[bg][il] = s;
    __syncthreads();
    if (tid < 64) {
        float t = b[blockIdx.x * 64 + tid];
        #pragma unroll
        for (int j = 0; j < 16; ++j) t += red[j][tid];
        out[blockIdx.x * 64 + tid] = fast_sigmoid(t);
    }
}

__global__ __launch_bounds__(256, 1) void nade_final_atomic(
    const float* __restrict__ logits,
    const float* __restrict__ b,
    float* __restrict__ out)
{
    const int i = blockIdx.x * 256 + threadIdx.x;
    out[i] = fast_sigmoid(logits[i] + b[i]);
}

extern "C" void kernel_launch(void* const* d_in, const int* in_sizes, int n_in,
                              void* d_out, int out_size, void* d_ws, size_t ws_size,
                              hipStream_t stream)
{
    const float* x = (const float*)d_in[0];
    const float* w = (const float*)d_in[1];
    const float* b = (const float*)d_in[2];
    const float* v = (const float*)d_in[3];
    const float* c = (const float*)d_in[4];
    float* out = (float*)d_out;
    float* ws  = (float*)d_ws;

    const size_t need = (size_t)NBLK * D_DIM * sizeof(float);
    if (ws_size >= need) {
        nade_main_kernel<false><<<NBLK, BLK, 0, stream>>>(x, w, v, c, ws);
        nade_reduce_kernel<<<D_DIM / 64, 1024, 0, stream>>>(ws, b, out);
    } else {
        hipMemsetAsync(d_ws, 0, D_DIM * sizeof(float), stream);
        nade_main_kernel<true><<<NBLK, BLK, 0, stream>>>(x, w, v, c, ws);
        nade_final_atomic<<<D_DIM / 256, 256, 0, stream>>>(ws, b, out);
    }
}